// Round 1
// baseline (388.883 us; speedup 1.0000x reference)
//
#include <hip/hip_runtime.h>

// StandardDeviationPooling: 4x4 windows, stride 2, VALID.
// in:  (64, 1024, 1024) fp32   out: (64, 511, 511) fp32
// std = sqrt(max(E[x^2] - E[x]^2, 0)), n = 16.

#define IN_H 1024
#define IN_W 1024
#define OUT_H 511
#define OUT_W 511

// Each thread computes a 4x4 tile of outputs.
// Block = 16x16 threads -> 64x64 outputs per block.
// Grid  = (8, 8, 64): 128x128 thread-tiles cover ceil(511/4)=128 per dim.
__global__ __launch_bounds__(256) void stdpool_kernel(
    const float* __restrict__ in, float* __restrict__ out) {
  const int tx = threadIdx.x;                 // 0..15
  const int ty = threadIdx.y;                 // 0..15
  const int tileX = blockIdx.x * 16 + tx;     // 0..127
  const int tileY = blockIdx.y * 16 + ty;     // 0..127
  const int b = blockIdx.z;

  const int wo0 = tileX * 4;                  // first output col of this thread
  const int ho0 = tileY * 4;                  // first output row
  const int col0 = wo0 * 2;                   // = 8*tileX, 32B-aligned
  const int row0 = ho0 * 2;

  const float* __restrict__ src = in + (size_t)b * IN_H * IN_W;

  float s[4][4];   // window sums
  float ss[4][4];  // window sums of squares
#pragma unroll
  for (int j = 0; j < 4; ++j)
#pragma unroll
    for (int c = 0; c < 4; ++c) {
      s[j][c] = 0.0f;
      ss[j][c] = 0.0f;
    }

  // Third (tail) load covers cols 8..9; only needed when output col wo0+3
  // exists (tileX <= 126). W = 1024 = 8*128, so the two float4 loads are
  // always in-bounds.
  const bool have_tail = (col0 + 9) < IN_W;

#pragma unroll
  for (int r = 0; r < 10; ++r) {
    const int rg = row0 + r;
    // Rows >= 1024 only feed output rows >= 511 (invalid) -> skip.
    if (rg < IN_H) {
      const float* __restrict__ rp = src + (size_t)rg * IN_W + col0;
      const float4 a = *(const float4*)(rp);
      const float4 d = *(const float4*)(rp + 4);
      float c8 = 0.0f, c9 = 0.0f;
      if (have_tail) {
        const float2 t = *(const float2*)(rp + 8);
        c8 = t.x;
        c9 = t.y;
      }
      const float cv[10] = {a.x, a.y, a.z, a.w, d.x, d.y, d.z, d.w, c8, c9};

      // Stride-2 width-4 horizontal window sums = adjacent pair sums.
      float p[5], q[5];
#pragma unroll
      for (int i = 0; i < 5; ++i) {
        p[i] = cv[2 * i] + cv[2 * i + 1];
        q[i] = cv[2 * i] * cv[2 * i] + cv[2 * i + 1] * cv[2 * i + 1];
      }
      float hw[4], hq[4];
#pragma unroll
      for (int c = 0; c < 4; ++c) {
        hw[c] = p[c] + p[c + 1];
        hq[c] = q[c] + q[c + 1];
      }

      // Input row r (relative) feeds output row j iff 2j <= r <= 2j+3.
#pragma unroll
      for (int j = 0; j < 4; ++j) {
        if (r >= 2 * j && r <= 2 * j + 3) {
#pragma unroll
          for (int c = 0; c < 4; ++c) {
            s[j][c] += hw[c];
            ss[j][c] += hq[c];
          }
        }
      }
    }
  }

  const float inv_n = 1.0f / 16.0f;
  float* __restrict__ obase = out + (size_t)b * OUT_H * OUT_W;
#pragma unroll
  for (int j = 0; j < 4; ++j) {
    const int ho = ho0 + j;
    if (ho < OUT_H) {
      float* __restrict__ orow = obase + (size_t)ho * OUT_W + wo0;
#pragma unroll
      for (int c = 0; c < 4; ++c) {
        const int wo = wo0 + c;
        if (wo < OUT_W) {
          const float mean = s[j][c] * inv_n;
          float var = ss[j][c] * inv_n - mean * mean;
          var = fmaxf(var, 0.0f);
          orow[c] = sqrtf(var);
        }
      }
    }
  }
}

extern "C" void kernel_launch(void* const* d_in, const int* in_sizes, int n_in,
                              void* d_out, int out_size, void* d_ws,
                              size_t ws_size, hipStream_t stream) {
  const float* x = (const float*)d_in[0];
  float* out = (float*)d_out;

  dim3 block(16, 16, 1);
  dim3 grid(8, 8, 64);  // 128x128 tiles of 4x4 outputs, 64 batches
  stdpool_kernel<<<grid, block, 0, stream>>>(x, out);
}